// Round 1
// baseline (16460.287 us; speedup 1.0000x reference)
//
#include <hip/hip_runtime.h>
#include <hip/hip_cooperative_groups.h>
#include <cmath>
#include <cstdint>

namespace cg = cooperative_groups;

#define VOCAB 32000
#define HID   1024
#define BATCH 16
#define SEQ   256

// ---------------------------------------------------------------------------
// pre0[s][b][n] = embed[x[b][s]] . Wi[0][n] + bi[0][n]
// GEMM: M=4096 (m = s*16+b), N=1024, K=1024, A-rows gathered via x.
// ---------------------------------------------------------------------------
__global__ __launch_bounds__(256) void pre0_gemm(
    const int* __restrict__ x, const float* __restrict__ embed,
    const float* __restrict__ Wi, const float* __restrict__ bi,
    float* __restrict__ pre0)
{
  __shared__ float As[32][132];
  __shared__ float Bs[32][132];
  const int tid  = threadIdx.x;
  const int n0   = blockIdx.x * 128;
  const int m0   = blockIdx.y * 128;
  const int lrow = tid >> 3, lkq = tid & 7;
  const int ty   = tid >> 4, tx  = tid & 15;

  const float* arow[4];
#pragma unroll
  for (int q = 0; q < 4; ++q) {
    int m = m0 + lrow + 32 * q;
    int s = m >> 4, b = m & 15;
    arow[q] = embed + (size_t)x[b * SEQ + s] * HID;
  }
  const float* brow = Wi + (size_t)(n0 + lrow) * HID;  // layer-0 rows

  float acc[8][8];
#pragma unroll
  for (int i = 0; i < 8; ++i)
#pragma unroll
    for (int j = 0; j < 8; ++j) acc[i][j] = 0.f;

  for (int kt = 0; kt < HID; kt += 32) {
    float4 av[4], bv[4];
#pragma unroll
    for (int q = 0; q < 4; ++q) {
      av[q] = *(const float4*)(arow[q] + kt + lkq * 4);
      bv[q] = *(const float4*)(brow + (size_t)(32 * q) * HID + kt + lkq * 4);
    }
    __syncthreads();                       // previous iter's compute done
#pragma unroll
    for (int q = 0; q < 4; ++q) {
      int r = lrow + 32 * q;
      As[lkq*4+0][r] = av[q].x; As[lkq*4+1][r] = av[q].y;
      As[lkq*4+2][r] = av[q].z; As[lkq*4+3][r] = av[q].w;
      Bs[lkq*4+0][r] = bv[q].x; Bs[lkq*4+1][r] = bv[q].y;
      Bs[lkq*4+2][r] = bv[q].z; Bs[lkq*4+3][r] = bv[q].w;
    }
    __syncthreads();
#pragma unroll
    for (int kk = 0; kk < 32; ++kk) {
      float4 a0 = *(const float4*)&As[kk][ty * 8];
      float4 a1 = *(const float4*)&As[kk][ty * 8 + 4];
      float4 b0 = *(const float4*)&Bs[kk][tx * 8];
      float4 b1 = *(const float4*)&Bs[kk][tx * 8 + 4];
      float a[8] = {a0.x,a0.y,a0.z,a0.w,a1.x,a1.y,a1.z,a1.w};
      float b[8] = {b0.x,b0.y,b0.z,b0.w,b1.x,b1.y,b1.z,b1.w};
#pragma unroll
      for (int i = 0; i < 8; ++i)
#pragma unroll
        for (int j = 0; j < 8; ++j) acc[i][j] = fmaf(a[i], b[j], acc[i][j]);
    }
  }

#pragma unroll
  for (int i = 0; i < 8; ++i) {
    int m = m0 + ty * 8 + i;
    float* o = pre0 + (size_t)m * HID + n0 + tx * 8;
#pragma unroll
    for (int j = 0; j < 8; ++j) o[j] = acc[i][j] + bi[n0 + tx * 8 + j];
  }
}

// ---------------------------------------------------------------------------
// logits[b][s][v] = tops[s][b][:] . Wo[v][:] + bo[v]
// GEMM: M=4096 (m = b*256+s so C-writes are contiguous), N=32000, K=1024.
// ---------------------------------------------------------------------------
__global__ __launch_bounds__(256) void proj_gemm(
    const float* __restrict__ tops, const float* __restrict__ Wo,
    const float* __restrict__ bo, float* __restrict__ out)
{
  __shared__ float As[32][132];
  __shared__ float Bs[32][132];
  const int tid  = threadIdx.x;
  const int n0   = blockIdx.x * 128;       // 250 blocks
  const int m0   = blockIdx.y * 128;       // 32 blocks
  const int lrow = tid >> 3, lkq = tid & 7;
  const int ty   = tid >> 4, tx  = tid & 15;

  const float* arow[4];
#pragma unroll
  for (int q = 0; q < 4; ++q) {
    int m = m0 + lrow + 32 * q;
    int b = m >> 8, s = m & 255;
    arow[q] = tops + (size_t)(s * BATCH + b) * HID;
  }
  const float* brow = Wo + (size_t)(n0 + lrow) * HID;

  float acc[8][8];
#pragma unroll
  for (int i = 0; i < 8; ++i)
#pragma unroll
    for (int j = 0; j < 8; ++j) acc[i][j] = 0.f;

  for (int kt = 0; kt < HID; kt += 32) {
    float4 av[4], bv[4];
#pragma unroll
    for (int q = 0; q < 4; ++q) {
      av[q] = *(const float4*)(arow[q] + kt + lkq * 4);
      bv[q] = *(const float4*)(brow + (size_t)(32 * q) * HID + kt + lkq * 4);
    }
    __syncthreads();
#pragma unroll
    for (int q = 0; q < 4; ++q) {
      int r = lrow + 32 * q;
      As[lkq*4+0][r] = av[q].x; As[lkq*4+1][r] = av[q].y;
      As[lkq*4+2][r] = av[q].z; As[lkq*4+3][r] = av[q].w;
      Bs[lkq*4+0][r] = bv[q].x; Bs[lkq*4+1][r] = bv[q].y;
      Bs[lkq*4+2][r] = bv[q].z; Bs[lkq*4+3][r] = bv[q].w;
    }
    __syncthreads();
#pragma unroll
    for (int kk = 0; kk < 32; ++kk) {
      float4 a0 = *(const float4*)&As[kk][ty * 8];
      float4 a1 = *(const float4*)&As[kk][ty * 8 + 4];
      float4 b0 = *(const float4*)&Bs[kk][tx * 8];
      float4 b1 = *(const float4*)&Bs[kk][tx * 8 + 4];
      float a[8] = {a0.x,a0.y,a0.z,a0.w,a1.x,a1.y,a1.z,a1.w};
      float b[8] = {b0.x,b0.y,b0.z,b0.w,b1.x,b1.y,b1.z,b1.w};
#pragma unroll
      for (int i = 0; i < 8; ++i)
#pragma unroll
        for (int j = 0; j < 8; ++j) acc[i][j] = fmaf(a[i], b[j], acc[i][j]);
    }
  }

#pragma unroll
  for (int i = 0; i < 8; ++i) {
    int m = m0 + ty * 8 + i;
    float* o = out + (size_t)m * VOCAB + n0 + tx * 8;
#pragma unroll
    for (int j = 0; j < 8; ++j) o[j] = acc[i][j] + bo[n0 + tx * 8 + j];
  }
}

// ---------------------------------------------------------------------------
// Persistent cooperative RNN scan, skewed pipeline:
//   tick u: layer0 computes step u  (h0[u] = tanh(pre0[u] + Wh0 h0[u-1] + bh0))
//           layer1 computes step u-1 (h1 = tanh(Wi1 h0[u-1] + Wh1 h1[u-2] + b))
// 256 blocks, block b owns rows [4b,4b+4) of both layers; weights in LDS.
// h0buf/h1buf are [2][16][1024] double buffers (parity = step & 1).
// ---------------------------------------------------------------------------
__global__ __launch_bounds__(256) void rnn_scan(
    const float* __restrict__ Wi, const float* __restrict__ Wh,
    const float* __restrict__ bi, const float* __restrict__ bh,
    const float* __restrict__ pre0, float* __restrict__ h0buf,
    float* __restrict__ h1buf, float* __restrict__ tops)
{
  cg::grid_group grid = cg::this_grid();
  __shared__ float w0[4][1024];   // Wh[0][r0+i][k]
  __shared__ float w1[4][2048];   // [Wi[1] | Wh[1]] rows
  __shared__ float bias0[4], bias1[4];

  const int tid = threadIdx.x;
  const int r0  = blockIdx.x * 4;

  for (int idx = tid; idx < 1024; idx += 256) {        // 4096 floats of w0
    int i = idx >> 8, kq = idx & 255;
    *(float4*)&w0[i][kq * 4] =
        *(const float4*)(Wh + (size_t)(r0 + i) * HID + kq * 4);
  }
  for (int idx = tid; idx < 2048; idx += 256) {        // 8192 floats of w1
    int i = idx >> 9, kq = idx & 511;
    const float* src = (kq < 256)
        ? (Wi + (size_t)(HID + r0 + i) * HID + kq * 4)
        : (Wh + (size_t)(HID + r0 + i) * HID + (kq - 256) * 4);
    *(float4*)&w1[i][kq * 4] = *(const float4*)src;
  }
  if (tid < 4) {
    bias0[tid] = bh[r0 + tid];                         // bh[0]
    bias1[tid] = bi[HID + r0 + tid] + bh[HID + r0 + tid];
  }
  __syncthreads();

  const int g  = tid >> 2, j = tid & 3;
  const int rr = g >> 4, cc = g & 15;
  const int row = r0 + rr;

  for (int u = 0; u <= SEQ; ++u) {
    if (u < SEQ) {   // ---- layer 0, step u ----
      const float* hsrc = h0buf + ((u - 1) & 1) * (BATCH * HID) + cc * HID + j * 256;
      const float* wsrc = &w0[rr][j * 256];
      float sum = 0.f;
#pragma unroll 8
      for (int i2 = 0; i2 < 64; ++i2) {
        float4 h4 = *(const float4*)(hsrc + i2 * 4);
        float4 w4 = *(const float4*)(wsrc + i2 * 4);
        sum = fmaf(h4.x, w4.x, sum); sum = fmaf(h4.y, w4.y, sum);
        sum = fmaf(h4.z, w4.z, sum); sum = fmaf(h4.w, w4.w, sum);
      }
      sum += __shfl_xor(sum, 1);
      sum += __shfl_xor(sum, 2);
      if (j == 0) {
        float v = tanhf(sum + pre0[(size_t)u * (BATCH * HID) + cc * HID + row] + bias0[rr]);
        h0buf[(u & 1) * (BATCH * HID) + cc * HID + row] = v;
      }
    }
    if (u >= 1) {    // ---- layer 1, step u-1 ----
      const int t = u - 1;
      const float* h0in   = h0buf + (t & 1) * (BATCH * HID);
      const float* h1prev = h1buf + ((t - 1) & 1) * (BATCH * HID);
      const float* hsrc = (j < 2) ? (h0in + cc * HID + j * 512)
                                  : (h1prev + cc * HID + (j - 2) * 512);
      const float* wsrc = &w1[rr][j * 512];
      float sum = 0.f;
#pragma unroll 8
      for (int i2 = 0; i2 < 128; ++i2) {
        float4 h4 = *(const float4*)(hsrc + i2 * 4);
        float4 w4 = *(const float4*)(wsrc + i2 * 4);
        sum = fmaf(h4.x, w4.x, sum); sum = fmaf(h4.y, w4.y, sum);
        sum = fmaf(h4.z, w4.z, sum); sum = fmaf(h4.w, w4.w, sum);
      }
      sum += __shfl_xor(sum, 1);
      sum += __shfl_xor(sum, 2);
      if (j == 0) {
        float v = tanhf(sum + bias1[rr]);
        tops[(size_t)t * (BATCH * HID) + cc * HID + row] = v;
        h1buf[(t & 1) * (BATCH * HID) + cc * HID + row] = v;
      }
    }
    grid.sync();
  }
}

// hidden[0] = h0 at step 255 (parity 1); hidden[1] = tops[255]
__global__ void copy_hidden(const float* __restrict__ h0buf,
                            const float* __restrict__ tops,
                            float* __restrict__ outh)
{
  int i = blockIdx.x * 256 + threadIdx.x;   // 0..32767
  int l = i >> 14, rem = i & 16383;
  outh[i] = (l == 0) ? h0buf[BATCH * HID + rem]
                     : tops[(size_t)(SEQ - 1) * (BATCH * HID) + rem];
}

extern "C" void kernel_launch(void* const* d_in, const int* in_sizes, int n_in,
                              void* d_out, int out_size, void* d_ws, size_t ws_size,
                              hipStream_t stream)
{
  const int*   x     = (const int*)d_in[0];
  const float* embed = (const float*)d_in[1];
  const float* Wi    = (const float*)d_in[2];
  const float* bi    = (const float*)d_in[3];
  const float* Wh    = (const float*)d_in[4];
  const float* bh    = (const float*)d_in[5];
  const float* Wo    = (const float*)d_in[6];
  const float* bo    = (const float*)d_in[7];
  float* out = (float*)d_out;

  char* ws = (char*)d_ws;
  float* pre0  = (float*)(ws);                               // 16 MiB
  float* tops  = (float*)(ws + 16777216);                    // 16 MiB
  float* h0buf = (float*)(ws + 2 * 16777216);                // 128 KiB
  float* h1buf = (float*)(ws + 2 * 16777216 + 131072);       // 128 KiB

  // zero both hidden double-buffers (initial state + deterministic replay)
  hipMemsetAsync(h0buf, 0, 262144, stream);

  dim3 blk(256);
  pre0_gemm<<<dim3(8, 32), blk, 0, stream>>>(x, embed, Wi, bi, pre0);

  void* args[] = { (void*)&Wi, (void*)&Wh, (void*)&bi, (void*)&bh,
                   (void*)&pre0, (void*)&h0buf, (void*)&h1buf, (void*)&tops };
  hipLaunchCooperativeKernel((void*)rnn_scan, dim3(256), blk, args, 0, stream);

  proj_gemm<<<dim3(250, 32), blk, 0, stream>>>(tops, Wo, bo, out);

  copy_hidden<<<dim3(128), blk, 0, stream>>>(h0buf, tops,
                                             out + (size_t)BATCH * SEQ * VOCAB);
}